// Round 11
// baseline (230.903 us; speedup 1.0000x reference)
//
#include <hip/hip_runtime.h>
#include <hip/hip_bf16.h>
#include <cmath>

#define BETA 0.3f
#define LAMBDA_PHY 0.15f

#define BM 128
#define BN 128
#define BK 64
#define NT 256

typedef __bf16 bf16x8 __attribute__((ext_vector_type(8)));
typedef float f32x4 __attribute__((ext_vector_type(4)));

#define AS1 __attribute__((address_space(1)))
#define AS3 __attribute__((address_space(3)))

#define FENCE() asm volatile("" ::: "memory")
#define BARRIER() do { FENCE(); __builtin_amdgcn_s_barrier(); FENCE(); } while (0)
#define WAITV8() asm volatile("s_waitcnt vmcnt(8)" ::: "memory")
#define WAITV0() asm volatile("s_waitcnt vmcnt(0)" ::: "memory")

__device__ __forceinline__ unsigned short f2bf_rn(float f) {
    unsigned int u = __builtin_bit_cast(unsigned int, f);
    return (unsigned short)((u + 0x7FFFu + ((u >> 16) & 1u)) >> 16);
}

__device__ __forceinline__ float bf2f(unsigned short u) {
    return __builtin_bit_cast(float, (unsigned int)u << 16);
}

__device__ __forceinline__ float softplus_f(float x) {
    return fmaxf(x, 0.0f) + __logf(1.0f + __expf(-fabsf(x)));
}

__device__ __forceinline__ float smooth_l1_f(float d) {
    float ad = fabsf(d);
    return (ad < BETA) ? (0.5f / BETA) * d * d : (ad - 0.5f * BETA);
}

// ---------------------------------------------------------------------------
// Kernel 1: adjacency (int32 ZxZ) -> bf16 mask (ZxZ, K-contig) + invdeg + hasnb
__global__ void k_prep(const int* __restrict__ adj, unsigned short* __restrict__ maskbf,
                       float* __restrict__ invdeg, float* __restrict__ hasnb, int Z) {
    int z = blockIdx.x;
    int t = threadIdx.x;
    const int* row = adj + (size_t)z * Z;
    unsigned short* mrow = maskbf + (size_t)z * Z;
    int cnt = 0;
    for (int n = t; n < Z; n += blockDim.x) {
        int a = (row[n] > 0);
        mrow[n] = a ? (unsigned short)0x3F80 : (unsigned short)0;  // bf16 1.0 / 0.0
        cnt += a;
    }
    for (int o = 32; o; o >>= 1) cnt += __shfl_down(cnt, o);
    __shared__ int rs[4];
    int lane = t & 63, wave = t >> 6;
    if (lane == 0) rs[wave] = cnt;
    __syncthreads();
    if (t == 0) {
        int deg = rs[0] + rs[1] + rs[2] + rs[3];
        invdeg[z] = (deg > 0) ? 1.0f / (float)deg : 1.0f;
        hasnb[z]  = (deg > 0) ? 1.0f : 0.0f;
    }
}

// ---------------------------------------------------------------------------
// Kernel 2: fp32 -> bf16 (RN), 8 elems/thread, vectorized
__global__ void k_conv(const float* __restrict__ src, uint4* __restrict__ dst, long n8) {
    long i = (long)blockIdx.x * blockDim.x + threadIdx.x;
    long stride = (long)gridDim.x * blockDim.x;
    for (; i < n8; i += stride) {
        const float4* s = (const float4*)(src + i * 8);
        float4 a = s[0], b = s[1];
        uint4 o;
        o.x = (unsigned)f2bf_rn(a.x) | ((unsigned)f2bf_rn(a.y) << 16);
        o.y = (unsigned)f2bf_rn(a.z) | ((unsigned)f2bf_rn(a.w) << 16);
        o.z = (unsigned)f2bf_rn(b.x) | ((unsigned)f2bf_rn(b.y) << 16);
        o.w = (unsigned)f2bf_rn(b.z) | ((unsigned)f2bf_rn(b.w) << 16);
        dst[i] = o;
    }
}

// ---------------------------------------------------------------------------
// Kernel 3: 128x128 bf16 GEMM, 4 waves (2x2), per-wave 64x64, 2 blocks/CU.
// Round-11: R10 was LDS-port-bound (12 ds_reads per 16 MFMA/wave/tile; total
// LDS 8.4 GB ~= 122us floor at 69 TB/s vs 55us MFMA). Per-wave 64x64 raises
// FLOP/LDS-byte 21->32: 16 ds_reads per 32 MFMA. NT=256 keeps LDS at 64.5 KB
// -> still 2 blocks/CU (2 waves/SIMD, one per block -> cross-block interleave).
// __launch_bounds__(256,2): 256 regs/wave; acc[4][4]=64 AGPR + transient frags
// -> no spill. Compile-time buffer unroll, counted vmcnt(8), T1+T2 swizzles.
__global__ __launch_bounds__(NT, 2) void k_gemm(
    const unsigned short* __restrict__ Abf,   // [M][K] bf16 ctemps
    const unsigned short* __restrict__ Bbf,   // [N][K] bf16 mask
    const float* __restrict__ preds,
    const float* __restrict__ targets,
    const float* __restrict__ invdeg,
    const float* __restrict__ hasnb,
    float* __restrict__ partials,
    int M, int N, int K)
{
    __shared__ unsigned short AsF[2 * BM * 64];   // 32 KB (buf stride 8192 elems)
    __shared__ unsigned short BsF[2 * BN * 64];   // 32 KB

    const int nwg = gridDim.x;
    const int ob = blockIdx.x;
    const int bid = (nwg % 8 == 0) ? ((ob % 8) * (nwg / 8) + ob / 8) : ob;  // T1
    const int ntiles = N / BN;
    const int mt = bid / ntiles;
    const int nt = bid % ntiles;
    const int row0 = mt * BM;
    const int col0 = nt * BN;
    const int t = threadIdx.x;
    const int lane = t & 63;
    const int wave = t >> 6;
    const int wm = wave >> 1;             // 2x2 wave grid; per-wave 64x64 out
    const int wn = wave & 1;
    const int fr = lane & 15;
    const int fq = lane >> 4;
    const int fr7 = fr & 7;

    // staging: thread t -> row tr (0..31, +32 per chunk), 16B slot tc;
    // source col-slot pre-swizzled (T2); 32%8==0 keeps cs valid per chunk.
    const int tr = t >> 3;                // 0..31
    const int tc = t & 7;                 // 16B slot 0..7
    const int cs = tc ^ (tr & 7);         // swizzled global col-slot

    // loop-invariant LDS read offsets (elements)
    const int colk0 = (fq ^ fr7) * 8;
    const int colk1 = ((4 + fq) ^ fr7) * 8;
    const int ofsA0 = (wm * 64 + fr) * 64 + colk0;
    const int ofsA1 = (wm * 64 + fr) * 64 + colk1;
    const int ofsB0 = (wn * 64 + fr) * 64 + colk0;
    const int ofsB1 = (wn * 64 + fr) * 64 + colk1;

    f32x4 acc[4][4];
#pragma unroll
    for (int m = 0; m < 4; ++m)
#pragma unroll
        for (int n = 0; n < 4; ++n)
            acc[m][n] = (f32x4){0.f, 0.f, 0.f, 0.f};

    // per-thread source pointers (advance by BK per staged tile)
    const unsigned short* aSrc = Abf + (size_t)(row0 + tr) * K + cs * 8;
    const unsigned short* bSrc = Bbf + (size_t)(col0 + tr) * K + cs * 8;
    unsigned short* aDstC = &AsF[t * 8];   // t*16 bytes within buf 0 (4 KB/chunk)
    unsigned short* bDstC = &BsF[t * 8];

#define STAGE(BUF) do {                                                                      \
    _Pragma("unroll")                                                                        \
    for (int r_ = 0; r_ < 4; ++r_)                                                           \
        __builtin_amdgcn_global_load_lds((const AS1 void*)(aSrc + (size_t)(r_ * 32) * K),    \
                                         (AS3 void*)(aDstC + (BUF) * 8192 + r_ * 2048), 16, 0, 0); \
    _Pragma("unroll")                                                                        \
    for (int r_ = 0; r_ < 4; ++r_)                                                           \
        __builtin_amdgcn_global_load_lds((const AS1 void*)(bSrc + (size_t)(r_ * 32) * K),    \
                                         (AS3 void*)(bDstC + (BUF) * 8192 + r_ * 2048), 16, 0, 0); \
    aSrc += BK; bSrc += BK;                                                                  \
} while (0)

// One kk half-step: 8 ds_reads (offset-imm from loop-invariant bases) + 16 MFMA.
#define MFMA_KK(BUF, OFSA, OFSB) do {                                                        \
    bf16x8 af_[4], bv_[4];                                                                   \
    _Pragma("unroll")                                                                        \
    for (int mi_ = 0; mi_ < 4; ++mi_)                                                        \
        af_[mi_] = *(const bf16x8*)(AsF + (BUF) * 8192 + (OFSA) + mi_ * 1024);               \
    _Pragma("unroll")                                                                        \
    for (int ni_ = 0; ni_ < 4; ++ni_)                                                        \
        bv_[ni_] = *(const bf16x8*)(BsF + (BUF) * 8192 + (OFSB) + ni_ * 1024);               \
    __builtin_amdgcn_s_setprio(1);                                                           \
    _Pragma("unroll")                                                                        \
    for (int mi_ = 0; mi_ < 4; ++mi_)                                                        \
    _Pragma("unroll")                                                                        \
    for (int ni_ = 0; ni_ < 4; ++ni_)                                                        \
        acc[mi_][ni_] = __builtin_amdgcn_mfma_f32_16x16x32_bf16(                             \
            af_[mi_], bv_[ni_], acc[mi_][ni_], 0, 0, 0);                                     \
    __builtin_amdgcn_s_setprio(0);                                                           \
} while (0)

    const int nk = K / BK;          // even (guarded in launch)
    const int nk2 = nk >> 1;
    STAGE(0);                        // tile 0 -> buf 0

    for (int i = 0; i < nk2; ++i) {
        // half A: compute buf0 (tile 2i), stage tile 2i+1 -> buf1
        STAGE(1);
        WAITV8();                    // retires tile 2i's 8 loads (oldest)
        BARRIER();
        MFMA_KK(0, ofsA0, ofsB0);
        MFMA_KK(0, ofsA1, ofsB1);
        BARRIER();
        // half B: compute buf1 (tile 2i+1), stage tile 2i+2 -> buf0
        if (i + 1 < nk2) {
            STAGE(0);
            WAITV8();                // retires tile 2i+1's 8 loads
        } else {
            WAITV0();
        }
        BARRIER();
        MFMA_KK(1, ofsA0, ofsB0);
        MFMA_KK(1, ofsA1, ofsB1);
        BARRIER();
    }

#undef STAGE
#undef MFMA_KK

    // Fused epilogue. C/D frag layout: col=lane&15, row=(lane>>4)*4+reg.
    // block row = wm*64 + m*16 + fq*4 + j ; block col = wn*64 + n*16 + fr
    float vsum = 0.f, ssum = 0.f;
#pragma unroll
    for (int n = 0; n < 4; ++n) {
        const int z = col0 + wn * 64 + n * 16 + fr;
        const float idg = invdeg[z];
        const float hnb = hasnb[z];
#pragma unroll
        for (int m = 0; m < 4; ++m) {
            const int rb = row0 + wm * 64 + m * 16 + fq * 4;
#pragma unroll
            for (int j = 0; j < 4; ++j) {
                const size_t idx = (size_t)(rb + j) * N + z;
                float avg = acc[m][n][j] * idg;
                float c = bf2f(Abf[idx]);          // bf16 ctemps (saves 1/3 fetch)
                float p = preds[idx];
                float tg = targets[idx];
                float x = (c - avg) * (p - c);
                vsum += softplus_f(x) * hnb;
                ssum += smooth_l1_f(p - tg);
            }
        }
    }
    for (int o = 32; o; o >>= 1) { vsum += __shfl_down(vsum, o); ssum += __shfl_down(ssum, o); }
    __shared__ float rv[4], rsm[4];
    if (lane == 0) { rv[wave] = vsum; rsm[wave] = ssum; }
    __syncthreads();
    if (t == 0) {
        partials[2 * (size_t)ob]     = rv[0] + rv[1] + rv[2] + rv[3];
        partials[2 * (size_t)ob + 1] = rsm[0] + rsm[1] + rsm[2] + rsm[3];
    }
}

// ---------------------------------------------------------------------------
// Kernel 4: deterministic fixed-order final reduction
__global__ void k_finalize(const float* __restrict__ partials, int nblk,
                           float* __restrict__ out, float invBZ) {
    __shared__ float sv[256], ss[256];
    int t = threadIdx.x;
    float v = 0.f, s = 0.f;
    for (int i = t; i < nblk; i += 256) { v += partials[2 * (size_t)i]; s += partials[2 * (size_t)i + 1]; }
    sv[t] = v; ss[t] = s;
    __syncthreads();
    for (int o = 128; o; o >>= 1) {
        if (t < o) { sv[t] += sv[t + o]; ss[t] += ss[t + o]; }
        __syncthreads();
    }
    if (t == 0) {
        float phys = sv[0] * invBZ;
        float pred = ss[0] * invBZ;
        out[0] = pred + LAMBDA_PHY * phys;
        out[1] = phys;
    }
}

// ---------------------------------------------------------------------------
// Fallback path (only if ws too small / odd shapes): fp32, atomics into ws[0..1]
__global__ void k_zero2(float* p) { if (threadIdx.x < 2) p[threadIdx.x] = 0.f; }

__global__ void k_fallback(const float* __restrict__ preds, const float* __restrict__ targets,
                           const float* __restrict__ ctemps, const int* __restrict__ adj,
                           float* __restrict__ acc2, int B, int Z) {
    extern __shared__ float crow[];
    int nzb = (Z + 255) / 256;
    int b = blockIdx.x / nzb;
    int zb = blockIdx.x % nzb;
    int t = threadIdx.x;
    const float* cr = ctemps + (size_t)b * Z;
    for (int n = t; n < Z; n += 256) crow[n] = cr[n];
    __syncthreads();
    int z = zb * 256 + t;
    float vsum = 0.f, ssum = 0.f;
    if (z < Z) {
        const int* arow = adj + (size_t)z * Z;
        float sum = 0.f; int deg = 0;
        for (int n = 0; n < Z; ++n) {
            if (arow[n] > 0) { sum += crow[n]; ++deg; }
        }
        float avg = (deg > 0) ? sum / (float)deg : 0.f;
        float c = crow[z];
        size_t idx = (size_t)b * Z + z;
        float p = preds[idx];
        float x = (c - avg) * (p - c);
        vsum = (deg > 0) ? softplus_f(x) : 0.f;
        ssum = smooth_l1_f(p - targets[idx]);
    }
    for (int o = 32; o; o >>= 1) { vsum += __shfl_down(vsum, o); ssum += __shfl_down(ssum, o); }
    __shared__ float rv[4], rs2[4];
    int lane = t & 63, wave = t >> 6;
    if (lane == 0) { rv[wave] = vsum; rs2[wave] = ssum; }
    __syncthreads();
    if (t == 0) {
        atomicAdd(&acc2[0], rv[0] + rv[1] + rv[2] + rv[3]);
        atomicAdd(&acc2[1], rs2[0] + rs2[1] + rs2[2] + rs2[3]);
    }
}

// ---------------------------------------------------------------------------
extern "C" void kernel_launch(void* const* d_in, const int* in_sizes, int n_in,
                              void* d_out, int out_size, void* d_ws, size_t ws_size,
                              hipStream_t stream) {
    const float* preds   = (const float*)d_in[0];
    const float* targets = (const float*)d_in[1];
    const float* ctemps  = (const float*)d_in[2];
    const int*   adj     = (const int*)d_in[3];
    float* out = (float*)d_out;

    long zz = in_sizes[3];
    int Z = (int)llround(sqrt((double)zz));
    int B = in_sizes[1] / Z;

    size_t off = 0;
    size_t maskOff = off; off += (size_t)Z * Z * 2;
    size_t cbfOff  = off; off += (size_t)B * Z * 2;
    size_t idgOff  = off; off += (size_t)Z * 4;
    size_t hnbOff  = off; off += (size_t)Z * 4;
    int nblk = (Z > 0 && B > 0 && (B % BM) == 0 && (Z % BN) == 0) ? (B / BM) * (Z / BN) : 0;
    size_t partOff = off; off += (size_t)(nblk > 0 ? nblk : 1) * 2 * 4;

    bool main_ok = (B % BM == 0) && (Z % BN == 0) && (Z % BK == 0) &&
                   (((Z / BK) % 2) == 0) && (ws_size >= off);

    float invBZ = (float)(1.0 / ((double)B * (double)Z));

    if (main_ok) {
        char* ws = (char*)d_ws;
        unsigned short* maskbf = (unsigned short*)(ws + maskOff);
        unsigned short* cbf    = (unsigned short*)(ws + cbfOff);
        float* idg      = (float*)(ws + idgOff);
        float* hnb      = (float*)(ws + hnbOff);
        float* partials = (float*)(ws + partOff);

        k_prep<<<Z, 256, 0, stream>>>(adj, maskbf, idg, hnb, Z);
        long n8 = (long)B * Z / 8;
        k_conv<<<2048, 256, 0, stream>>>(ctemps, (uint4*)cbf, n8);
        k_gemm<<<nblk, NT, 0, stream>>>(cbf, maskbf, preds, targets, idg, hnb, partials, B, Z, Z);
        k_finalize<<<1, 256, 0, stream>>>(partials, nblk, out, invBZ);
    } else {
        float* acc2 = (float*)d_ws;
        k_zero2<<<1, 64, 0, stream>>>(acc2);
        int nzb = (Z + 255) / 256;
        k_fallback<<<B * nzb, 256, (size_t)Z * 4, stream>>>(preds, targets, ctemps, adj, acc2, B, Z);
        k_finalize<<<1, 256, 0, stream>>>(acc2, 1, out, invBZ);
    }
}